// Round 8
// baseline (533.600 us; speedup 1.0000x reference)
//
#include <hip/hip_runtime.h>

#define N_NODES 100000
#define N_EDGES 600000
#define DIM 128

typedef unsigned short ushortT;
typedef __attribute__((ext_vector_type(8))) short short8;
typedef __attribute__((ext_vector_type(4))) float float4v;
typedef __attribute__((ext_vector_type(4))) unsigned int uint4v;

__device__ __forceinline__ float bf2f(ushortT h) {
    return __builtin_bit_cast(float, ((unsigned int)h) << 16);
}
__device__ __forceinline__ float bflo(unsigned int p) {
    return __builtin_bit_cast(float, p << 16);
}
__device__ __forceinline__ float bfhi(unsigned int p) {
    return __builtin_bit_cast(float, p & 0xffff0000u);
}
__device__ __forceinline__ ushortT f2bf(float f) {  // RNE
    unsigned int x = __builtin_bit_cast(unsigned int, f);
    unsigned int r = (x + 0x7fffu + ((x >> 16) & 1u)) >> 16;
    return (ushortT)r;
}

// ---- prep: W (128x128 f32, KxN) -> WH (transposed + XOR-swizzled bf16, for LDS)
//                                    WL (plain transposed bf16 residual, read from global)
__global__ __launch_bounds__(256) void prep_kernel(const float* __restrict__ W1,
                                                   const float* __restrict__ W2,
                                                   ushortT* __restrict__ wt) {
    const float* Wf = (blockIdx.x == 0) ? W1 : W2;
    ushortT* outh = wt + blockIdx.x * 32768;
    ushortT* outl = outh + 16384;
    int t = threadIdx.x;
#pragma unroll
    for (int i = 0; i < 16; i++) {
        int c = t + i * 256;            // 0..4095
        int k = c >> 5;
        int n0 = (c & 31) * 4;
        float4v w = *(const float4v*)(Wf + k * 128 + n0);
        int g = k >> 3, kk = k & 7;
#pragma unroll
        for (int j = 0; j < 4; j++) {
            int n = n0 + j;
            ushortT wh = f2bf(w[j]);
            ushortT wl = f2bf(w[j] - bf2f(wh));
            outh[n * 128 + ((g ^ (n & 15)) << 3) + kk] = wh;
            outl[n * 128 + k] = wl;
        }
    }
}

// ---- x (f32) -> bf16 plane, once per call ----
__global__ __launch_bounds__(256) void xbf_kernel(const float* __restrict__ x,
                                                  ushortT* __restrict__ xb) {
    int i = blockIdx.x * 256 + threadIdx.x;  // 8-elem group; grid exact (6250)
    float4v a = ((const float4v*)x)[2 * i];
    float4v b = ((const float4v*)x)[2 * i + 1];
    ushortT o[8];
#pragma unroll
    for (int j = 0; j < 4; j++) o[j] = f2bf(a[j]);
#pragma unroll
    for (int j = 0; j < 4; j++) o[4 + j] = f2bf(b[j]);
    ((uint4v*)xb)[i] = *(const uint4v*)o;
}

// ---- CSR build ----
__global__ __launch_bounds__(256) void hist_kernel(const int* __restrict__ dst,
                                                   int* __restrict__ counts) {
    int e = blockIdx.x * 256 + threadIdx.x;
    if (e < N_EDGES) atomicAdd(&counts[dst[e]], 1);
}

#define SCAN_BLOCKS 98  // 98*1024 >= 100000

__global__ __launch_bounds__(1024) void blockscan_kernel(const int* __restrict__ counts,
                                                         int* __restrict__ local,
                                                         int* __restrict__ bsums) {
    __shared__ int wsum[16];
    int tid = threadIdx.x, lane = tid & 63, wid = tid >> 6;
    int i = blockIdx.x * 1024 + tid;
    int v = (i < N_NODES) ? counts[i] : 0;
    int incl = v;
#pragma unroll
    for (int off = 1; off < 64; off <<= 1) {
        int u = __shfl_up(incl, off);
        if (lane >= off) incl += u;
    }
    if (lane == 63) wsum[wid] = incl;
    __syncthreads();
    if (wid == 0) {
        int s = (lane < 16) ? wsum[lane] : 0;
#pragma unroll
        for (int off = 1; off < 16; off <<= 1) {
            int u = __shfl_up(s, off);
            if (lane >= off) s += u;
        }
        if (lane < 16) wsum[lane] = s;
    }
    __syncthreads();
    int excl = ((wid == 0) ? 0 : wsum[wid - 1]) + incl - v;
    if (i < N_NODES) local[i] = excl;
    if (tid == 0) bsums[blockIdx.x] = wsum[15];
}

__global__ __launch_bounds__(1024) void fixup_kernel(const int* __restrict__ local,
                                                     const int* __restrict__ bsums,
                                                     int* __restrict__ offsets,
                                                     int* __restrict__ cursor) {
    __shared__ int sbase;
    int tid = threadIdx.x;
    if (tid < 64) {
        int s = 0;
        for (int j = tid; j < blockIdx.x; j += 64) s += bsums[j];
#pragma unroll
        for (int off = 32; off >= 1; off >>= 1) s += __shfl_xor(s, off);
        if (tid == 0) sbase = s;
    }
    __syncthreads();
    int base = sbase;
    int i = blockIdx.x * 1024 + tid;
    if (i < N_NODES) {
        int o = local[i] + base;
        offsets[i] = o;
        cursor[i] = o;
    }
    if (blockIdx.x == 0 && tid == 0) offsets[N_NODES] = N_EDGES;
}

__global__ __launch_bounds__(256) void fill_kernel(const int* __restrict__ src,
                                                   const int* __restrict__ dst,
                                                   int* __restrict__ cursor,
                                                   int* __restrict__ eidx) {
    int e = blockIdx.x * 256 + threadIdx.x;
    if (e < N_EDGES) {
        int pos = atomicAdd(&cursor[dst[e]], 1);
        eidx[pos] = src[e];
    }
}

// ---- aggregation: one wave per node; z[v] = h[v] + sum neighbors (h is bf16 plane).
// Output: interleaved bf16 hi/lo planes, node stride 256 ushorts (hi +0, lo +128).
__global__ __launch_bounds__(256) void agg_kernel(const ushortT* __restrict__ h,
                                                  const int* __restrict__ offsets,
                                                  const int* __restrict__ eidx,
                                                  ushortT* __restrict__ z) {
    int w = blockIdx.x * 4 + (threadIdx.x >> 6);  // node id; grid exact (25000 blocks)
    w = __builtin_amdgcn_readfirstlane(w);
    int lane = threadIdx.x & 63;
    const ushortT* hp = h + lane * 2;
    int beg = offsets[w], end = offsets[w + 1];
    int cnt = end - beg;
    unsigned int p0 = *(const unsigned int*)(hp + (size_t)w * DIM);
    float ax = bflo(p0), ay = bfhi(p0);
    for (int base = 0; base < cnt; base += 8) {
        int idx[8];
#pragma unroll
        for (int j = 0; j < 8; j++) {
            int q = base + j;
            if (q > cnt - 1) q = cnt - 1;
            idx[j] = eidx[beg + q];
        }
        unsigned int v[8];
#pragma unroll
        for (int j = 0; j < 8; j++) v[j] = *(const unsigned int*)(hp + (size_t)idx[j] * DIM);
        int rem = cnt - base;  // wave-uniform
#pragma unroll
        for (int j = 0; j < 8; j++)
            if (j < rem) { ax += bflo(v[j]); ay += bfhi(v[j]); }
    }
    ushortT hx = f2bf(ax), hy = f2bf(ay);
    float lx = ax - bf2f(hx), ly = ay - bf2f(hy);
    unsigned int hi = (unsigned int)hx | ((unsigned int)hy << 16);
    unsigned int lo = (unsigned int)f2bf(lx) | ((unsigned int)f2bf(ly) << 16);
    *(unsigned int*)(z + (size_t)w * 256 + lane * 2)       = hi;
    *(unsigned int*)(z + (size_t)w * 256 + 128 + lane * 2) = lo;
}

// GEMM: out = act(A @ W + bias), K=N=128, 3-term bf16-split (AhWh + AlWh + AhWl).
// A: interleaved bf16 hi/lo planes, row stride 256 ushorts. 16 rows per wave, no
// barrier in K-loop. WH staged in LDS (swizzled), WL streamed from global (L2-hot).
// Epilogue transposes through the (dead) WH LDS region -> fully coalesced stores.
// OUT 0: interleaved hi/lo bf16 (stride 256) + relu. OUT 1: bf16 plane (128) + relu.
// OUT 2: f32 (stride 128), no relu.
template <int OUT>
__global__ __launch_bounds__(256) void gemm_kernel(const ushortT* __restrict__ A,
                                                   const ushortT* __restrict__ wtH,
                                                   const ushortT* __restrict__ wtL,
                                                   const float* __restrict__ bias,
                                                   void* __restrict__ out) {
    __shared__ ushortT SH[17408];  // 34816 B: [0,16384) WH stage; transpose at wid*4352

    int t = threadIdx.x, lane = t & 63, wid = t >> 6;
    int unit = blockIdx.x * 4 + wid;  // 16-row unit; 6250 total (exact)
    int quad = lane >> 4, col16 = lane & 15;
    bool active = unit < (N_NODES / 16);
    int row0 = unit * 16;

    // A prefetch: 8 independent b128 loads
    short8 ah[4], al[4];
    if (active) {
        const ushortT* ap = A + (size_t)(row0 + col16) * 256 + quad * 8;
#pragma unroll
        for (int s = 0; s < 4; s++) {
            ah[s] = *(const short8*)(ap + s * 32);
            al[s] = *(const short8*)(ap + s * 32 + 128);
        }
    }

    // stage WH (swizzled image): coalesced, conflict-free
#pragma unroll
    for (int i = 0; i < 8; i++) {
        int idx = (t + i * 256) * 8;
        *(uint4v*)&SH[idx] = *(const uint4v*)&wtH[idx];
    }
    __syncthreads();

    float bia[8];
    float4v acc[8];
    if (active) {
#pragma unroll
        for (int n = 0; n < 8; n++) bia[n] = bias[n * 16 + col16];
#pragma unroll
        for (int n = 0; n < 8; n++) acc[n] = (float4v)0.0f;
#pragma unroll
        for (int s = 0; s < 4; s++) {
#pragma unroll
            for (int n = 0; n < 8; n++) {
                short8 bh = *(const short8*)&SH[(n * 16 + col16) * 128 + (((s * 4 + quad) ^ col16) << 3)];
                short8 bl = *(const short8*)&wtL[(n * 16 + col16) * 128 + s * 32 + quad * 8];
                acc[n] = __builtin_amdgcn_mfma_f32_16x16x32_bf16(ah[s], bh, acc[n], 0, 0, 0);
                acc[n] = __builtin_amdgcn_mfma_f32_16x16x32_bf16(al[s], bh, acc[n], 0, 0, 0);
                acc[n] = __builtin_amdgcn_mfma_f32_16x16x32_bf16(ah[s], bl, acc[n], 0, 0, 0);
            }
        }
    }
    __syncthreads();  // WH region dead only after all waves finish K-loop

    if (!active) return;

    // epilogue via per-wave LDS transpose (C/D layout: col=lane&15 within n-block, row=quad*4+i)
    ushortT* tr = &SH[wid * 4352];
    if constexpr (OUT == 0) {
#pragma unroll
        for (int n = 0; n < 8; n++)
#pragma unroll
            for (int i = 0; i < 4; i++) {
                float v = acc[n][i] + bia[n];
                v = v > 0.0f ? v : 0.0f;
                int row = quad * 4 + i, col = n * 16 + col16;
                ushortT hi = f2bf(v);
                tr[row * 264 + col]       = hi;
                tr[row * 264 + 128 + col] = f2bf(v - bf2f(hi));
            }
#pragma unroll
        for (int p = 0; p < 8; p++) {
            int row = p * 2 + (lane >> 5);
            int seg = lane & 31;
            uint4v val = *(const uint4v*)&tr[row * 264 + seg * 8];
            *(uint4v*)((ushortT*)out + (size_t)(row0 + row) * 256 + seg * 8) = val;
        }
    } else if constexpr (OUT == 1) {
#pragma unroll
        for (int n = 0; n < 8; n++)
#pragma unroll
            for (int i = 0; i < 4; i++) {
                float v = acc[n][i] + bia[n];
                v = v > 0.0f ? v : 0.0f;
                tr[(quad * 4 + i) * 136 + n * 16 + col16] = f2bf(v);
            }
#pragma unroll
        for (int p = 0; p < 4; p++) {
            int row = p * 4 + (lane >> 4);
            int seg = lane & 15;
            uint4v val = *(const uint4v*)&tr[row * 136 + seg * 8];
            *(uint4v*)((ushortT*)out + (size_t)(row0 + row) * 128 + seg * 8) = val;
        }
    } else {
        float* trf = (float*)tr;  // stride 132 floats
#pragma unroll
        for (int n = 0; n < 8; n++)
#pragma unroll
            for (int i = 0; i < 4; i++)
                trf[(quad * 4 + i) * 132 + n * 16 + col16] = acc[n][i] + bia[n];
#pragma unroll
        for (int p = 0; p < 8; p++) {
            int row = p * 2 + (lane >> 5);
            int seg = lane & 31;
            float4v val = *(const float4v*)&trf[row * 132 + seg * 4];
            *(float4v*)((float*)out + (size_t)(row0 + row) * 128 + seg * 4) = val;
        }
    }
}

extern "C" void kernel_launch(void* const* d_in, const int* in_sizes, int n_in,
                              void* d_out, int out_size, void* d_ws, size_t ws_size,
                              hipStream_t stream) {
    const float* x  = (const float*)d_in[0];
    const int* src  = (const int*)d_in[1];
    const int* dst  = (const int*)d_in[2];
    const float* W1 = (const float*)d_in[3];
    const float* b1 = (const float*)d_in[4];
    const float* W2 = (const float*)d_in[5];
    const float* b2 = (const float*)d_in[6];

    ushortT* zbuf = (ushortT*)d_out;  // d_out doubles as interleaved bf16 z (51.2MB)

    char* ws = (char*)d_ws;
    ushortT* wt     = (ushortT*)ws;                        // 128 KB: W1H|W1L|W2H|W2L
    int*     offs   = (int*)(ws + 131072);                 // 100001 ints
    int*     cursor = (int*)(ws + 531456);                 // 100000 ints
    int*     eidx   = (int*)(ws + 931456);                 // 600000 ints
    int*     local  = (int*)(ws + 3331456);                // 100000 ints
    int*     bsums  = (int*)(ws + 3731456);                // 98 ints
    ushortT* xbf    = (ushortT*)(ws + 3731968);            // 25.6 MB bf16 x
    ushortT* hidbuf = (ushortT*)(ws + 3731968 + 25600000); // 51.2 MB interleaved hi/lo
    ushortT* hbf    = (ushortT*)(ws + 3731968 + 76800000); // 25.6 MB bf16 h
    // total ~106.1 MB

    const ushortT* w1h = wt;
    const ushortT* w1l = wt + 16384;
    const ushortT* w2h = wt + 32768;
    const ushortT* w2l = wt + 49152;

    dim3 blk(256);
    const int gEdge = (N_EDGES + 255) / 256;    // 2344
    const int gAgg  = N_NODES / 4;              // 25000 exact (1 wave/node)
    const int gGemm = (N_NODES / 16 + 3) / 4;   // 1563 (6250 16-row units)
    const int gXbf  = N_NODES * DIM / 8 / 256;  // 6250 exact

    prep_kernel<<<2, blk, 0, stream>>>(W1, W2, wt);
    xbf_kernel<<<gXbf, blk, 0, stream>>>(x, xbf);
    hipMemsetAsync(cursor, 0, N_NODES * sizeof(int), stream);
    hist_kernel<<<gEdge, blk, 0, stream>>>(dst, cursor);
    blockscan_kernel<<<SCAN_BLOCKS, 1024, 0, stream>>>(cursor, local, bsums);
    fixup_kernel<<<SCAN_BLOCKS, 1024, 0, stream>>>(local, bsums, offs, cursor);
    fill_kernel<<<gEdge, blk, 0, stream>>>(src, dst, cursor, eidx);

    // layer 0
    agg_kernel<<<gAgg, blk, 0, stream>>>(xbf, offs, eidx, zbuf);
    gemm_kernel<0><<<gGemm, blk, 0, stream>>>(zbuf, w1h, w1l, b1, hidbuf);
    gemm_kernel<1><<<gGemm, blk, 0, stream>>>(hidbuf, w2h, w2l, b2, hbf);
    // layer 1
    agg_kernel<<<gAgg, blk, 0, stream>>>(hbf, offs, eidx, zbuf);
    gemm_kernel<0><<<gGemm, blk, 0, stream>>>(zbuf, w1h, w1l, b1, hidbuf);
    gemm_kernel<1><<<gGemm, blk, 0, stream>>>(hidbuf, w2h, w2l, b2, hbf);
    // layer 2 (final: f32 to d_out, no relu)
    agg_kernel<<<gAgg, blk, 0, stream>>>(hbf, offs, eidx, zbuf);
    gemm_kernel<0><<<gGemm, blk, 0, stream>>>(zbuf, w1h, w1l, b1, hidbuf);
    gemm_kernel<2><<<gGemm, blk, 0, stream>>>(hidbuf, w2h, w2l, b2, (float*)d_out);
}

// Round 9
// 433.714 us; speedup vs baseline: 1.2303x; 1.2303x over previous
//
#include <hip/hip_runtime.h>

#define N_NODES 100000
#define N_EDGES 600000
#define DIM 128

typedef unsigned short ushortT;
typedef __attribute__((ext_vector_type(8))) short short8;
typedef __attribute__((ext_vector_type(4))) float float4v;
typedef __attribute__((ext_vector_type(4))) unsigned int uint4v;

__device__ __forceinline__ float bf2f(ushortT h) {
    return __builtin_bit_cast(float, ((unsigned int)h) << 16);
}
__device__ __forceinline__ float bflo(unsigned int p) {
    return __builtin_bit_cast(float, p << 16);
}
__device__ __forceinline__ float bfhi(unsigned int p) {
    return __builtin_bit_cast(float, p & 0xffff0000u);
}
__device__ __forceinline__ ushortT f2bf(float f) {  // RNE
    unsigned int x = __builtin_bit_cast(unsigned int, f);
    unsigned int r = (x + 0x7fffu + ((x >> 16) & 1u)) >> 16;
    return (ushortT)r;
}

// ---- prep: W (128x128 f32, KxN) -> transposed + XOR-swizzled bf16 hi/lo images
// element (k,n) stored at  n*128 + (((k>>3) ^ (n&15))<<3) + (k&7)
__global__ __launch_bounds__(256) void prep_kernel(const float* __restrict__ W1,
                                                   const float* __restrict__ W2,
                                                   ushortT* __restrict__ wt) {
    const float* Wf = (blockIdx.x == 0) ? W1 : W2;
    ushortT* outh = wt + blockIdx.x * 32768;
    ushortT* outl = outh + 16384;
    int t = threadIdx.x;
#pragma unroll
    for (int i = 0; i < 16; i++) {
        int c = t + i * 256;            // 0..4095
        int k = c >> 5;
        int n0 = (c & 31) * 4;
        float4v w = *(const float4v*)(Wf + k * 128 + n0);
        int g = k >> 3, kk = k & 7;
#pragma unroll
        for (int j = 0; j < 4; j++) {
            int n = n0 + j;
            ushortT wh = f2bf(w[j]);
            ushortT wl = f2bf(w[j] - bf2f(wh));
            int addr = n * 128 + ((g ^ (n & 15)) << 3) + kk;
            outh[addr] = wh;
            outl[addr] = wl;
        }
    }
}

// ---- x (f32) -> bf16 plane, once per call ----
__global__ __launch_bounds__(256) void xbf_kernel(const float* __restrict__ x,
                                                  ushortT* __restrict__ xb) {
    int i = blockIdx.x * 256 + threadIdx.x;  // 8-elem group; grid exact (6250)
    float4v a = ((const float4v*)x)[2 * i];
    float4v b = ((const float4v*)x)[2 * i + 1];
    ushortT o[8];
#pragma unroll
    for (int j = 0; j < 4; j++) o[j] = f2bf(a[j]);
#pragma unroll
    for (int j = 0; j < 4; j++) o[4 + j] = f2bf(b[j]);
    ((uint4v*)xb)[i] = *(const uint4v*)o;
}

// ---- CSR build ----
__global__ __launch_bounds__(256) void hist_kernel(const int* __restrict__ dst,
                                                   int* __restrict__ counts) {
    int e = blockIdx.x * 256 + threadIdx.x;
    if (e < N_EDGES) atomicAdd(&counts[dst[e]], 1);
}

#define SCAN_BLOCKS 98  // 98*1024 >= 100000

__global__ __launch_bounds__(1024) void blockscan_kernel(const int* __restrict__ counts,
                                                         int* __restrict__ local,
                                                         int* __restrict__ bsums) {
    __shared__ int wsum[16];
    int tid = threadIdx.x, lane = tid & 63, wid = tid >> 6;
    int i = blockIdx.x * 1024 + tid;
    int v = (i < N_NODES) ? counts[i] : 0;
    int incl = v;
#pragma unroll
    for (int off = 1; off < 64; off <<= 1) {
        int u = __shfl_up(incl, off);
        if (lane >= off) incl += u;
    }
    if (lane == 63) wsum[wid] = incl;
    __syncthreads();
    if (wid == 0) {
        int s = (lane < 16) ? wsum[lane] : 0;
#pragma unroll
        for (int off = 1; off < 16; off <<= 1) {
            int u = __shfl_up(s, off);
            if (lane >= off) s += u;
        }
        if (lane < 16) wsum[lane] = s;
    }
    __syncthreads();
    int excl = ((wid == 0) ? 0 : wsum[wid - 1]) + incl - v;
    if (i < N_NODES) local[i] = excl;
    if (tid == 0) bsums[blockIdx.x] = wsum[15];
}

__global__ __launch_bounds__(1024) void fixup_kernel(const int* __restrict__ local,
                                                     const int* __restrict__ bsums,
                                                     int* __restrict__ offsets,
                                                     int* __restrict__ cursor) {
    __shared__ int sbase;
    int tid = threadIdx.x;
    if (tid < 64) {
        int s = 0;
        for (int j = tid; j < blockIdx.x; j += 64) s += bsums[j];
#pragma unroll
        for (int off = 32; off >= 1; off >>= 1) s += __shfl_xor(s, off);
        if (tid == 0) sbase = s;
    }
    __syncthreads();
    int base = sbase;
    int i = blockIdx.x * 1024 + tid;
    if (i < N_NODES) {
        int o = local[i] + base;
        offsets[i] = o;
        cursor[i] = o;
    }
    if (blockIdx.x == 0 && tid == 0) offsets[N_NODES] = N_EDGES;
}

__global__ __launch_bounds__(256) void fill_kernel(const int* __restrict__ src,
                                                   const int* __restrict__ dst,
                                                   int* __restrict__ cursor,
                                                   int* __restrict__ eidx) {
    int e = blockIdx.x * 256 + threadIdx.x;
    if (e < N_EDGES) {
        int pos = atomicAdd(&cursor[dst[e]], 1);
        eidx[pos] = src[e];
    }
}

// ---- aggregation: one wave per node; z[v] = h[v] + sum neighbors (h is bf16 plane).
// Output: interleaved bf16 hi/lo planes, node stride 256 ushorts (hi +0, lo +128).
__global__ __launch_bounds__(256) void agg_kernel(const ushortT* __restrict__ h,
                                                  const int* __restrict__ offsets,
                                                  const int* __restrict__ eidx,
                                                  ushortT* __restrict__ z) {
    int w = blockIdx.x * 4 + (threadIdx.x >> 6);  // node id; grid exact (25000 blocks)
    w = __builtin_amdgcn_readfirstlane(w);
    int lane = threadIdx.x & 63;
    const ushortT* hp = h + lane * 2;
    int beg = offsets[w], end = offsets[w + 1];
    int cnt = end - beg;
    unsigned int p0 = *(const unsigned int*)(hp + (size_t)w * DIM);
    float ax = bflo(p0), ay = bfhi(p0);
    for (int base = 0; base < cnt; base += 8) {
        int idx[8];
#pragma unroll
        for (int j = 0; j < 8; j++) {
            int q = base + j;
            if (q > cnt - 1) q = cnt - 1;
            idx[j] = eidx[beg + q];
        }
        unsigned int v[8];
#pragma unroll
        for (int j = 0; j < 8; j++) v[j] = *(const unsigned int*)(hp + (size_t)idx[j] * DIM);
        int rem = cnt - base;  // wave-uniform
#pragma unroll
        for (int j = 0; j < 8; j++)
            if (j < rem) { ax += bflo(v[j]); ay += bfhi(v[j]); }
    }
    ushortT hx = f2bf(ax), hy = f2bf(ay);
    float lx = ax - bf2f(hx), ly = ay - bf2f(hy);
    unsigned int hi = (unsigned int)hx | ((unsigned int)hy << 16);
    unsigned int lo = (unsigned int)f2bf(lx) | ((unsigned int)f2bf(ly) << 16);
    *(unsigned int*)(z + (size_t)w * 256 + lane * 2)       = hi;
    *(unsigned int*)(z + (size_t)w * 256 + 128 + lane * 2) = lo;
}

// GEMM: out = act(A @ W + bias), K=N=128, 3-term bf16-split (AhWh + AlWh + AhWl).
// A: interleaved bf16 hi/lo planes, row stride 256 ushorts. 32 rows per wave.
// WH+WL both in 64KB LDS (swizzled). Per s-step: ALL 16 B-frags batched into
// registers (one lgkmcnt wait), then 48 MFMAs. __launch_bounds__(256,2) gives the
// compiler ~256 VGPRs so the batch actually hoists (R8 failed at 60 VGPRs).
// Epilogue: 2 passes of 16 rows through dead W LDS -> coalesced b128 stores.
// OUT 0: interleaved hi/lo bf16 (stride 256) + relu. OUT 1: bf16 plane (128) + relu.
// OUT 2: f32 (stride 128), no relu.
template <int OUT>
__global__ __launch_bounds__(256, 2) void gemm_kernel(const ushortT* __restrict__ A,
                                                      const ushortT* __restrict__ wtHL,
                                                      const float* __restrict__ bias,
                                                      void* __restrict__ out) {
    __shared__ ushortT SH[32768];  // 64KB: WH image [0,16384), WL image [16384,32768)

    int t = threadIdx.x, lane = t & 63, wid = t >> 6;
    int unit = blockIdx.x * 4 + wid;  // 32-row unit; 3125 total
    int quad = lane >> 4, col16 = lane & 15;
    bool active = unit < (N_NODES / 32);
    int row0 = unit * 32;

    float bia[8];
#pragma unroll
    for (int n = 0; n < 8; n++) bia[n] = bias[n * 16 + col16];

    // A prefetch: 32 independent b128 loads (issued before staging, covered by barrier)
    short8 ah[4][2], al[4][2];
    if (active) {
#pragma unroll
        for (int r = 0; r < 2; r++) {
            const ushortT* ap = A + (size_t)(row0 + r * 16 + col16) * 256 + quad * 8;
#pragma unroll
            for (int s = 0; s < 4; s++) {
                ah[s][r] = *(const short8*)(ap + s * 32);
                al[s][r] = *(const short8*)(ap + s * 32 + 128);
            }
        }
    }

    // stage WH+WL images: coalesced b128
#pragma unroll
    for (int i = 0; i < 16; i++) {
        int idx = (t + i * 256) * 8;
        *(uint4v*)&SH[idx] = *(const uint4v*)&wtHL[idx];
    }
    __syncthreads();

    float4v acc[2][8];
    if (active) {
#pragma unroll
        for (int r = 0; r < 2; r++)
#pragma unroll
            for (int n = 0; n < 8; n++) acc[r][n] = (float4v)0.0f;
#pragma unroll
        for (int s = 0; s < 4; s++) {
            // batch all 16 B-frag LDS reads -> single wait, then MFMA burst
            short8 bh[8], bl[8];
#pragma unroll
            for (int n = 0; n < 8; n++) {
                int addr = (n * 16 + col16) * 128 + (((s * 4 + quad) ^ col16) << 3);
                bh[n] = *(const short8*)&SH[addr];
                bl[n] = *(const short8*)&SH[16384 + addr];
            }
#pragma unroll
            for (int r = 0; r < 2; r++)
#pragma unroll
                for (int n = 0; n < 8; n++) {
                    acc[r][n] = __builtin_amdgcn_mfma_f32_16x16x32_bf16(ah[s][r], bh[n], acc[r][n], 0, 0, 0);
                    acc[r][n] = __builtin_amdgcn_mfma_f32_16x16x32_bf16(al[s][r], bh[n], acc[r][n], 0, 0, 0);
                    acc[r][n] = __builtin_amdgcn_mfma_f32_16x16x32_bf16(ah[s][r], bl[n], acc[r][n], 0, 0, 0);
                }
        }
    }
    __syncthreads();  // W region dead after all waves' K-loops
    if (!active) return;

    // epilogue: C/D layout col=lane&15 (within n-block), row=quad*4+i.
    // Two 16-row passes through per-wave LDS scratch -> coalesced stores.
#pragma unroll
    for (int r = 0; r < 2; r++) {
        if constexpr (OUT == 0) {
            ushortT* tr = &SH[wid * 4352];
#pragma unroll
            for (int n = 0; n < 8; n++)
#pragma unroll
                for (int i = 0; i < 4; i++) {
                    float v = acc[r][n][i] + bia[n];
                    v = v > 0.0f ? v : 0.0f;
                    int row = quad * 4 + i, col = n * 16 + col16;
                    ushortT hi = f2bf(v);
                    tr[row * 264 + col]       = hi;
                    tr[row * 264 + 128 + col] = f2bf(v - bf2f(hi));
                }
            __builtin_amdgcn_s_waitcnt(0);  // lgkm drain (per-wave scratch)
#pragma unroll
            for (int p = 0; p < 8; p++) {
                int row = p * 2 + (lane >> 5);
                int seg = lane & 31;
                uint4v val = *(const uint4v*)&tr[row * 264 + seg * 8];
                *(uint4v*)((ushortT*)out + (size_t)(row0 + r * 16 + row) * 256 + seg * 8) = val;
            }
        } else if constexpr (OUT == 1) {
            ushortT* tr = &SH[wid * 2304];
#pragma unroll
            for (int n = 0; n < 8; n++)
#pragma unroll
                for (int i = 0; i < 4; i++) {
                    float v = acc[r][n][i] + bia[n];
                    v = v > 0.0f ? v : 0.0f;
                    tr[(quad * 4 + i) * 136 + n * 16 + col16] = f2bf(v);
                }
            __builtin_amdgcn_s_waitcnt(0);
#pragma unroll
            for (int p = 0; p < 4; p++) {
                int row = p * 4 + (lane >> 4);
                int seg = lane & 15;
                uint4v val = *(const uint4v*)&tr[row * 136 + seg * 8];
                *(uint4v*)((ushortT*)out + (size_t)(row0 + r * 16 + row) * 128 + seg * 8) = val;
            }
        } else {
            float* trf = (float*)&SH[wid * 4352];  // stride 132 floats
#pragma unroll
            for (int n = 0; n < 8; n++)
#pragma unroll
                for (int i = 0; i < 4; i++)
                    trf[(quad * 4 + i) * 132 + n * 16 + col16] = acc[r][n][i] + bia[n];
            __builtin_amdgcn_s_waitcnt(0);
#pragma unroll
            for (int p = 0; p < 8; p++) {
                int row = p * 2 + (lane >> 5);
                int seg = lane & 31;
                float4v val = *(const float4v*)&trf[row * 132 + seg * 4];
                *(float4v*)((float*)out + (size_t)(row0 + r * 16 + row) * 128 + seg * 4) = val;
            }
        }
        if (r == 0) __builtin_amdgcn_s_waitcnt(0);  // WAR guard before pass 2 overwrite
    }
}

extern "C" void kernel_launch(void* const* d_in, const int* in_sizes, int n_in,
                              void* d_out, int out_size, void* d_ws, size_t ws_size,
                              hipStream_t stream) {
    const float* x  = (const float*)d_in[0];
    const int* src  = (const int*)d_in[1];
    const int* dst  = (const int*)d_in[2];
    const float* W1 = (const float*)d_in[3];
    const float* b1 = (const float*)d_in[4];
    const float* W2 = (const float*)d_in[5];
    const float* b2 = (const float*)d_in[6];

    ushortT* zbuf = (ushortT*)d_out;  // d_out doubles as interleaved bf16 z (51.2MB)

    char* ws = (char*)d_ws;
    ushortT* wt     = (ushortT*)ws;                        // 128 KB: W1H|W1L|W2H|W2L (swizzled)
    int*     offs   = (int*)(ws + 131072);                 // 100001 ints
    int*     cursor = (int*)(ws + 531456);                 // 100000 ints
    int*     eidx   = (int*)(ws + 931456);                 // 600000 ints
    int*     local  = (int*)(ws + 3331456);                // 100000 ints
    int*     bsums  = (int*)(ws + 3731456);                // 98 ints
    ushortT* xbf    = (ushortT*)(ws + 3731968);            // 25.6 MB bf16 x
    ushortT* hidbuf = (ushortT*)(ws + 3731968 + 25600000); // 51.2 MB interleaved hi/lo
    ushortT* hbf    = (ushortT*)(ws + 3731968 + 76800000); // 25.6 MB bf16 h
    // total ~106.1 MB

    const ushortT* w1 = wt;          // WH at +0, WL at +16384
    const ushortT* w2 = wt + 32768;  // WH at +0, WL at +16384

    dim3 blk(256);
    const int gEdge = (N_EDGES + 255) / 256;    // 2344
    const int gAgg  = N_NODES / 4;              // 25000 exact (1 wave/node)
    const int gGemm = (N_NODES / 32 + 3) / 4;   // 782 (3125 32-row units)
    const int gXbf  = N_NODES * DIM / 8 / 256;  // 6250 exact

    prep_kernel<<<2, blk, 0, stream>>>(W1, W2, wt);
    xbf_kernel<<<gXbf, blk, 0, stream>>>(x, xbf);
    hipMemsetAsync(cursor, 0, N_NODES * sizeof(int), stream);
    hist_kernel<<<gEdge, blk, 0, stream>>>(dst, cursor);
    blockscan_kernel<<<SCAN_BLOCKS, 1024, 0, stream>>>(cursor, local, bsums);
    fixup_kernel<<<SCAN_BLOCKS, 1024, 0, stream>>>(local, bsums, offs, cursor);
    fill_kernel<<<gEdge, blk, 0, stream>>>(src, dst, cursor, eidx);

    // layer 0
    agg_kernel<<<gAgg, blk, 0, stream>>>(xbf, offs, eidx, zbuf);
    gemm_kernel<0><<<gGemm, blk, 0, stream>>>(zbuf, w1, b1, hidbuf);
    gemm_kernel<1><<<gGemm, blk, 0, stream>>>(hidbuf, w2, b2, hbf);
    // layer 1
    agg_kernel<<<gAgg, blk, 0, stream>>>(hbf, offs, eidx, zbuf);
    gemm_kernel<0><<<gGemm, blk, 0, stream>>>(zbuf, w1, b1, hidbuf);
    gemm_kernel<1><<<gGemm, blk, 0, stream>>>(hidbuf, w2, b2, hbf);
    // layer 2 (final: f32 to d_out, no relu)
    agg_kernel<<<gAgg, blk, 0, stream>>>(hbf, offs, eidx, zbuf);
    gemm_kernel<0><<<gGemm, blk, 0, stream>>>(zbuf, w1, b1, hidbuf);
    gemm_kernel<2><<<gGemm, blk, 0, stream>>>(hidbuf, w2, b2, (float*)d_out);
}